// Round 13
// baseline (213.126 us; speedup 1.0000x reference)
//
#include <hip/hip_runtime.h>
#include <float.h>
#include <math.h>

#define B_ 2
#define C_ 64
#define HW 64
#define M1 62
#define NP (M1*M1)      // 3844
#define WIN 30
#define KK 5
#define NSEL 16
#define HS 128

#define OUT_SCORE_SZ (B_*KK*HS*HS)       // 163840
#define OUT_IDX_OFF  (OUT_SCORE_SZ)
#define OUT_IDX_SZ   (B_*NP*KK)          // 38440
#define OUT_DIFF_OFF (OUT_IDX_OFF+OUT_IDX_SZ)
#define OUT_DIFF_SZ  (B_*KK*C_*HS*HS)    // 10485760

// ws layout in floats
#define WS_XNP 0
#define WS_YNP 8192
#define WS_TOP 16384                      // ints: B_*NP*16 = 123008
#define WS_SV  (16384+123008)             // 139392
#define WS_DSUM (139392+40960)            // 180352
#define WS_XPM  (180352+2460160)          // 2640512
#define XPM_F   (B_*NP*576)               // 4428288 floats
#define WS_YPM  (WS_XPM + XPM_F)          // 7068800
#define WS_YPBF (WS_YPM + XPM_F)          // 11497088 (ushorts: B_*NP*576)
#define WS_XEBF (WS_YPBF + XPM_F/2)       // 13711232 (ushorts: B_*64*64*64)
#define WS_END  (WS_XEBF + 262144)        // 13973376
#define WS_NEED_BYTES ((size_t)WS_END * 4)   // ~55.9 MB

typedef __attribute__((ext_vector_type(8))) short bf16x8;
typedef __attribute__((ext_vector_type(4))) short bf16x4;
typedef __attribute__((ext_vector_type(4))) short s16x4;
typedef __attribute__((ext_vector_type(4))) float f32x4;

__device__ __forceinline__ unsigned short f2bf(float f) {
    union { float f; unsigned int u; } v; v.f = f;
    unsigned int r = (v.u + 0x7FFFu + ((v.u >> 16) & 1u)) >> 16;
    return (unsigned short)r;
}

__device__ __forceinline__ bf16x8 ld_bf8(const short* p) {
    bf16x4 lo = *(const bf16x4*)p;
    bf16x4 hi = *(const bf16x4*)(p + 4);
    bf16x8 r;
    r[0] = lo[0]; r[1] = lo[1]; r[2] = lo[2]; r[3] = lo[3];
    r[4] = hi[0]; r[5] = hi[1]; r[6] = hi[2]; r[7] = hi[3];
    return r;
}

// ---------------- K-1: xe -> pixel-major bf16 copy xebf[b][h][w][c] ---------
__global__ __launch_bounds__(256) void prep_xebf_kernel(const float* __restrict__ xe,
                                                        unsigned int* __restrict__ xebfW) {
    __shared__ float tile[64 * 65];
    const int bid = blockIdx.x;           // b*64 + h
    const int b = bid >> 6, h = bid & 63;
    const int tid = threadIdx.x;
    for (int i = tid; i < 4096; i += 256) {
        int c = i >> 6, w = i & 63;
        tile[c * 65 + w] = xe[(((size_t)b * C_ + c) * HW + h) * HW + w];
    }
    __syncthreads();
    for (int j = tid; j < 2048; j += 256) {
        int w = j >> 5, cp = j & 31;
        unsigned int u = (unsigned int)f2bf(tile[(2 * cp) * 65 + w])
                       | ((unsigned int)f2bf(tile[(2 * cp + 1) * 65 + w]) << 16);
        xebfW[(((size_t)b * HW + h) * HW + w) * 32 + cp] = u;
    }
}

// ---------------- K0: im2patch (f32 patch-major + permuted bf16 y) ----------
__global__ __launch_bounds__(256) void im2patch_kernel(const float* __restrict__ xe,
                                                       const float* __restrict__ ye,
                                                       float* __restrict__ xpm,
                                                       float* __restrict__ ypm,
                                                       unsigned int* __restrict__ ypbfW) {
    __shared__ float rows[64 * 192];
    __shared__ int tabL[576];
    __shared__ int tabP[576];
    const int tid = threadIdx.x;
    const int bid = blockIdx.x;
    const int srcI = bid / (B_ * M1);
    const int rem = bid - srcI * (B_ * M1);
    const int b = rem / M1, r = rem - b * M1;
    const float* src = (srcI ? ye : xe) + (size_t)b * C_ * HW * HW;
    float* dst = (srcI ? ypm : xpm) + (size_t)(b * NP + r * M1) * 576;

    for (int t = tid; t < 576; t += 256) {
        int c = t / 9, p = t - c * 9;
        tabL[t] = c * 192 + (p / 3) * 64 + (p % 3);
        int cj = (t / 144) * 16 + (t & 15), pj = (t % 144) >> 4;   // decode j
        tabP[t] = cj * 192 + (pj / 3) * 64 + (pj % 3);
    }
    for (int i = tid; i < 64 * 192; i += 256) {
        rows[i] = src[(i / 192) * (HW * HW) + r * HW + (i % 192)];
    }
    __syncthreads();

    for (int s = 0; s < M1; s++) {
        float* d = dst + s * 576;
        for (int e = tid; e < 576; e += 256) d[e] = rows[tabL[e] + s];
        if (srcI) {
            unsigned int* yb = ypbfW + (size_t)(b * NP + r * M1 + s) * 288;
            for (int j2 = tid; j2 < 288; j2 += 256) {
                unsigned int u = (unsigned int)f2bf(rows[tabP[2 * j2] + s])
                               | ((unsigned int)f2bf(rows[tabP[2 * j2 + 1] + s]) << 16);
                yb[j2] = u;
            }
        }
    }
}

// ---------------- K1: numpy-pairwise norms (bitwise np emulation) ------------
__global__ __launch_bounds__(256) void norm_np_kernel(const float* __restrict__ xe,
                                                      const float* __restrict__ ye,
                                                      float* __restrict__ xnp,
                                                      float* __restrict__ ynp) {
    __shared__ int tab[576];
    for (int t = threadIdx.x; t < 576; t += 256) {
        int c = t / 9, p = t - c * 9;
        tab[t] = c * (HW * HW) + (p / 3) * HW + (p % 3);
    }
    __syncthreads();

    int gid = blockIdx.x * 256 + threadIdx.x;
    if (gid >= 2 * B_ * NP * 8) return;
    int which = gid / (B_ * NP * 8);
    int rem = gid - which * (B_ * NP * 8);
    int patch = rem >> 3, leaf = rem & 7;
    int b = patch / NP, m = patch - b * NP;
    int r = m / M1, s = m - r * M1;
    const float* src = (which ? ye : xe) + (size_t)b * C_ * HW * HW + r * HW + s;

    int base = leaf * 72;
    float a8[8];
    #pragma unroll
    for (int i = 0; i < 8; i++) {
        float v = src[tab[base + i]];
        a8[i] = v * v;
    }
    for (int i0 = 8; i0 < 72; i0 += 8) {
        #pragma unroll
        for (int i = 0; i < 8; i++) {
            float v = src[tab[base + i0 + i]];
            a8[i] += v * v;
        }
    }
    float t = ((a8[0] + a8[1]) + (a8[2] + a8[3])) + ((a8[4] + a8[5]) + (a8[6] + a8[7]));
    t = t + __shfl_xor(t, 1, 8);
    t = t + __shfl_xor(t, 2, 8);
    t = t + __shfl_xor(t, 4, 8);
    if (leaf == 0) (which ? ynp : xnp)[patch] = t;
}

// ---------------- K2: MFMA prescreen, 16-ch chunks, 2 blocks/CU -------------
#define UPC2 40
#define CSTR2 20
#define YSTR2 580
#define ZOFF_SH (16*YSTR2)
#define YS2_OFF 56000
#define XN2_OFF (YS2_OFF + (ZOFF_SH+16)*2)
#define SM2_BYTES (XN2_OFF + 1089*4)

__global__ __launch_bounds__(512, 4) void gemm_select_kernel(const float* __restrict__ xe,
                                                             const float* __restrict__ ye,
                                                             const unsigned short* __restrict__ ypbf,
                                                             const unsigned short* __restrict__ xebf,
                                                             const float* __restrict__ xnp,
                                                             int* __restrict__ top_ws,
                                                             int use_pm) {
    __shared__ __align__(16) unsigned char smem[SM2_BYTES];
    short* xsS = (short*)smem;
    unsigned int* xsW = (unsigned int*)smem;
    short* ysS = (short*)(smem + YS2_OFF);
    float* xnL = (float*)(smem + XN2_OFF);
    float* Dl  = (float*)smem;

    const int bid = blockIdx.x;
    const int b  = bid >> 8;
    const int t  = bid & 255;
    const int r0 = (t >> 4) * 4;
    const int s0 = (t & 15) * 4;
    const int u0r = min(max(r0 - 15, 0), 32);
    const int u0c = min(max(s0 - 15, 0), 32);
    const int g0c = min(u0c & ~3, 24);
    const int cofs = u0c - g0c;
    const int tid = threadIdx.x;
    const int l   = tid & 63;
    const int wid = tid >> 6;
    const int lq  = l & 15;
    const int kg  = l >> 4;
    const int kgh = kg >> 1, kgl = kg & 1;

    // --- stage y patches (permuted layout) ---
    if (use_pm) {
        for (int u = tid; u < 16 * 144; u += 512) {
            int q = u / 144, j4 = u - q * 144;
            int rq = min(r0 + (q >> 2), 61), sq = min(s0 + (q & 3), 61);
            s16x4 v = *(const s16x4*)(ypbf + (size_t)(b * NP + rq * M1 + sq) * 576 + j4 * 4);
            *(s16x4*)(ysS + q * YSTR2 + j4 * 4) = v;
        }
    } else {
        for (int u = tid; u < 16 * 576; u += 512) {
            int q = u / 576, e = u - q * 576;
            int rq = min(r0 + (q >> 2), 61), sq = min(s0 + (q & 3), 61);
            int c = e / 9, p = e - c * 9;
            float v = ye[((b * C_ + c) * HW + rq + p / 3) * HW + sq + p % 3];
            ysS[q * YSTR2 + (c >> 4) * 144 + p * 16 + (c & 15)] = (short)f2bf(v);
        }
    }
    if (tid < 16) ysS[ZOFF_SH + tid] = 0;
    for (int i = tid; i < 1089; i += 512) {
        int cr = i / 33, cc = i - cr * 33;
        int nr = min(u0r + cr, 61), nc = min(u0c + cc, 61);
        xnL[i] = xnp[b * NP + nr * M1 + nc];
    }

    f32x4 acc[10];
    #pragma unroll
    for (int i = 0; i < 10; i++) acc[i] = (f32x4){0.f, 0.f, 0.f, 0.f};

    const int PI0[4] = {0, 0, 1, 2}, PJ0[4] = {0, 2, 1, 0};
    const int PI1[4] = {0, 1, 1, 2}, PJ1[4] = {1, 0, 2, 1};

    int prb[10], pcb[10];
    #pragma unroll
    for (int i = 0; i < 10; i++) {
        int ci = (wid * 10 + i) * 16 + lq;
        int cis = min(ci, 1088);
        int cr = cis / 33;
        prb[i] = cr;
        pcb[i] = cis - cr * 33 + cofs;
    }

    for (int chunk = 0; chunk < 4; chunk++) {
        __syncthreads();
        if (use_pm) {
            // pure short4 copies from pixel-major bf16 (no conversion VALU)
            for (int u = tid; u < 35 * 40 * 4; u += 512) {
                int pix = u >> 2, q4 = u & 3;
                int row = pix / 40, col = pix - row * 40;
                int gr = min(u0r + row, 63);
                s16x4 v = *(const s16x4*)(xebf + ((((size_t)b * HW + gr) * HW + g0c + col) << 6)
                                          + chunk * 16 + q4 * 4);
                *(s16x4*)(xsS + pix * CSTR2 + q4 * 4) = v;
            }
        } else {
            for (int u = tid; u < 560; u += 512) {
                int cp = u & 7, rh = u >> 3;
                int row = rh % 35, half = rh / 35;
                int c0 = chunk * 16 + cp * 2;
                int gr = min(u0r + row, 63);
                const float4* pa = (const float4*)(xe + ((size_t)(b * C_ + c0) * HW + gr) * HW + g0c);
                const float4* pb = (const float4*)(xe + ((size_t)(b * C_ + c0 + 1) * HW + gr) * HW + g0c);
                #pragma unroll
                for (int bb = 0; bb < 5; bb++) {
                    int blk = half * 5 + bb;
                    float4 va = pa[blk], vb = pb[blk];
                    int w0 = (row * UPC2 + blk * 4) * (CSTR2 / 2) + cp;
                    xsW[w0     ] = (unsigned)f2bf(va.x) | ((unsigned)f2bf(vb.x) << 16);
                    xsW[w0 + 10] = (unsigned)f2bf(va.y) | ((unsigned)f2bf(vb.y) << 16);
                    xsW[w0 + 20] = (unsigned)f2bf(va.z) | ((unsigned)f2bf(vb.z) << 16);
                    xsW[w0 + 30] = (unsigned)f2bf(va.w) | ((unsigned)f2bf(vb.w) << 16);
                }
            }
        }
        __syncthreads();

        // t4 OUTER / candidate-tile INNER (one af live; per-acc order unchanged)
        const int aBase = lq * YSTR2 + chunk * 144;
        #pragma unroll
        for (int t4 = 0; t4 < 5; t4++) {
            bf16x8 af;
            int pi, pj;
            if (t4 < 4) {
                int p = 2 * t4 + kgh;
                af = ld_bf8(ysS + aBase + p * 16 + kgl * 8);
                pi = kgh ? PI1[t4] : PI0[t4];
                pj = kgh ? PJ1[t4] : PJ0[t4];
            } else {
                af = ld_bf8(ysS + ((kg < 2) ? (aBase + 8 * 16 + kgl * 8) : (ZOFF_SH + kgl * 8)));
                pi = 2; pj = 2;
            }
            #pragma unroll
            for (int i = 0; i < 10; i++) {
                bf16x8 bf = ld_bf8(xsS + ((prb[i] + pi) * UPC2 + (pcb[i] + pj)) * CSTR2 + kgl * 8);
                acc[i] = __builtin_amdgcn_mfma_f32_16x16x32_bf16(af, bf, acc[i], 0, 0, 0);
            }
        }
    }

    __syncthreads();
    #pragma unroll
    for (int i = 0; i < 10; i++) {
        int ci = (wid * 10 + i) * 16 + lq;
        if (ci < 1089) {
            float xnv = xnL[ci];
            #pragma unroll
            for (int j = 0; j < 4; j++) {
                Dl[(kg * 4 + j) * 1089 + ci] = xnv - 2.0f * acc[i][j];
            }
        }
    }
    __syncthreads();

    // packed-u32 top-16: key = (truncated sortable f32 << 10) | w
    for (int qq = 0; qq < 2; qq++) {
        int q = wid * 2 + qq;
        int rq = r0 + (q >> 2), sq = s0 + (q & 3);
        if (rq > 61 || sq > 61) continue;
        int siq = min(max(rq - 15, 0), 32);
        int sjq = min(max(sq - 15, 0), 32);
        int ro = siq - u0r, co = sjq - u0c;
        unsigned int kv[15];
        #pragma unroll
        for (int kk = 0; kk < 15; kk++) {
            int w = kk * 64 + l;
            if (w < 900) {
                int wi = w / 30, wj = w - wi * 30;
                float v = Dl[q * 1089 + (ro + wi) * 33 + (co + wj)];
                unsigned int u = __float_as_uint(v);
                u ^= (unsigned int)((int)u >> 31) | 0x80000000u;
                kv[kk] = (u & 0xFFFFFC00u) | (unsigned int)w;
            } else kv[kk] = 0xFFFFFFFFu;
        }
        int obase = (b * NP + rq * M1 + sq) * NSEL;
        for (int it = 0; it < NSEL; it++) {
            unsigned int lm = kv[0];
            #pragma unroll
            for (int kk = 1; kk < 15; kk++) lm = min(lm, kv[kk]);
            #pragma unroll
            for (int off = 32; off >= 1; off >>= 1)
                lm = min(lm, (unsigned int)__shfl_xor((int)lm, off));
            if (l == 0) {
                int w = (int)(lm & 1023u);
                int wi = w / 30, wj = w - wi * 30;
                top_ws[obase + it] = (siq + wi) * M1 + (sjq + wj);
            }
            #pragma unroll
            for (int kk = 0; kk < 15; kk++)
                if (kv[kk] == lm) kv[kk] = 0xFFFFFFFFu;
        }
    }
}

// ---------------- K3a: emu from patch-major buffers (dense reads) -----------
__global__ __launch_bounds__(256) void emu_pm_kernel(const float* __restrict__ xpm,
                                                     const float* __restrict__ ypm,
                                                     const float* __restrict__ xnp,
                                                     const float* __restrict__ ynp,
                                                     const int* __restrict__ top_ws,
                                                     float* __restrict__ out_idx,
                                                     float* __restrict__ sv_ws,
                                                     float* __restrict__ dsum_ws) {
    __shared__ float ysE[576];
    __shared__ int topWs[NSEL];
    __shared__ float keyEmu[NSEL];
    __shared__ float selKey[KK];
    __shared__ int   selN[KK];

    const int bid0 = blockIdx.x;
    const int bid = (bid0 & 7) * (B_ * NP / 8) + (bid0 >> 3);  // XCD-affine
    const int b = bid / NP, m = bid - b * NP;
    const int tid = threadIdx.x;
    const float* ybase = ypm + (size_t)(b * NP + m) * 576;

    for (int t = tid; t < 576; t += 256) ysE[t] = ybase[t];
    if (tid < NSEL) topWs[tid] = top_ws[bid * NSEL + tid];
    __syncthreads();

    {
        const int cand = tid >> 4, j = tid & 15;
        const float* xp = xpm + (size_t)(b * NP + topWs[cand]) * 576;
        float acc = 0.f;
        #pragma unroll
        for (int t = 0; t < 36; t++) {
            int e = t * 16 + j;
            acc = fmaf(ysE[e], xp[e], acc);
        }
        float E = acc;
        E = E + __shfl_xor(E, 8, 16);
        E = E + __shfl_xor(E, 4, 16);
        E = E + __shfl_xor(E, 2, 16);
        E = E + __shfl_xor(E, 1, 16);
        if (j == 0) {
            float t0 = -2.0f * E;
            float k1 = t0 + ynp[b * NP + m];
            float k2 = k1 + xnp[b * NP + topWs[cand]];
            keyEmu[cand] = k2 + 1e-5f;
        }
    }
    __syncthreads();

    if (tid == 0) {
        float d[NSEL]; int w[NSEL];
        for (int i = 0; i < NSEL; i++) { d[i] = keyEmu[i]; w[i] = topWs[i]; }
        for (int a = 1; a < NSEL; a++) {
            float dv = d[a]; int wv2 = w[a]; int p = a - 1;
            while (p >= 0 && (d[p] > dv || (d[p] == dv && w[p] > wv2))) {
                d[p + 1] = d[p]; w[p + 1] = w[p]; p--;
            }
            d[p + 1] = dv; w[p + 1] = wv2;
        }
        for (int i = 0; i < KK; i++) { selKey[i] = d[i]; selN[i] = w[i]; }
    }
    __syncthreads();

    if (tid < KK) {
        out_idx[(b * NP + m) * KK + tid] = (float)selN[tid];
        float s10 = selKey[tid] / 10.0f;
        double sv = exp(-(double)s10);
        sv_ws[(b * KK + tid) * NP + m] = (float)sv;
    }

    for (int pair = tid; pair < KK * C_; pair += 256) {
        int k = pair >> 6, c = pair & 63;
        const float* xrow = xpm + (size_t)(b * NP + selN[k]) * 576 + c * 9;
        const float* yrow = ysE + c * 9;
        float a = 0.f;
        #pragma unroll
        for (int p = 0; p < 9; p++) a += fabsf(yrow[p] - xrow[p]);
        dsum_ws[((b * KK + k) * C_ + c) * NP + m] = a;
    }
}

// ---------------- K3b: fallback emu (scattered) ------------------------------
#define XCSTR 584

__global__ __launch_bounds__(256) void emu_fallback_kernel(const float* __restrict__ xe,
                                                           const float* __restrict__ ye,
                                                           const float* __restrict__ xnp,
                                                           const float* __restrict__ ynp,
                                                           const int* __restrict__ top_ws,
                                                           float* __restrict__ out_idx,
                                                           float* __restrict__ sv_ws,
                                                           float* __restrict__ dsum_ws) {
    __shared__ float ysE[576];
    __shared__ int tab[576];
    __shared__ float xc[NSEL * XCSTR];
    __shared__ int topWs[NSEL];
    __shared__ float keyEmu[NSEL];
    __shared__ float selKey[KK];
    __shared__ int   selN[KK];
    __shared__ int   selI[KK];

    const int bid0 = blockIdx.x;
    const int bid = (bid0 & 7) * (B_ * NP / 8) + (bid0 >> 3);
    const int b = bid / NP, m = bid - b * NP;
    const int r = m / M1, s = m - r * M1;
    const int tid = threadIdx.x;
    const float* xb = xe + (size_t)b * C_ * HW * HW;
    const float* yb = ye + (size_t)b * C_ * HW * HW + r * HW + s;

    for (int t = tid; t < 576; t += 256) {
        int c = t / 9, p = t - c * 9;
        tab[t] = c * (HW * HW) + (p / 3) * HW + (p % 3);
    }
    if (tid < NSEL) topWs[tid] = top_ws[bid * NSEL + tid];
    __syncthreads();

    for (int t = tid; t < 576; t += 256) ysE[t] = yb[tab[t]];
    for (int i = tid; i < NSEL * 576; i += 256) {
        int cand = i / 576, e = i - cand * 576;
        int n = topWs[cand];
        int px = n / M1, py = n - px * M1;
        xc[cand * XCSTR + e] = xb[px * HW + py + tab[e]];
    }
    __syncthreads();

    {
        const int cand = tid >> 4, j = tid & 15;
        const float* xcp = xc + cand * XCSTR;
        float acc = 0.f;
        #pragma unroll
        for (int t = 0; t < 36; t++) {
            int e = t * 16 + j;
            acc = fmaf(ysE[e], xcp[e], acc);
        }
        float E = acc;
        E = E + __shfl_xor(E, 8, 16);
        E = E + __shfl_xor(E, 4, 16);
        E = E + __shfl_xor(E, 2, 16);
        E = E + __shfl_xor(E, 1, 16);
        if (j == 0) {
            float t0 = -2.0f * E;
            float k1 = t0 + ynp[b * NP + m];
            float k2 = k1 + xnp[b * NP + topWs[cand]];
            keyEmu[cand] = k2 + 1e-5f;
        }
    }
    __syncthreads();

    if (tid == 0) {
        float d[NSEL]; int w[NSEL]; int ix[NSEL];
        for (int i = 0; i < NSEL; i++) { d[i] = keyEmu[i]; w[i] = topWs[i]; ix[i] = i; }
        for (int a = 1; a < NSEL; a++) {
            float dv = d[a]; int wv2 = w[a]; int iv = ix[a]; int p = a - 1;
            while (p >= 0 && (d[p] > dv || (d[p] == dv && w[p] > wv2))) {
                d[p + 1] = d[p]; w[p + 1] = w[p]; ix[p + 1] = ix[p]; p--;
            }
            d[p + 1] = dv; w[p + 1] = wv2; ix[p + 1] = iv;
        }
        for (int i = 0; i < KK; i++) { selKey[i] = d[i]; selN[i] = w[i]; selI[i] = ix[i]; }
    }
    __syncthreads();

    if (tid < KK) {
        out_idx[(b * NP + m) * KK + tid] = (float)selN[tid];
        float s10 = selKey[tid] / 10.0f;
        double sv = exp(-(double)s10);
        sv_ws[(b * KK + tid) * NP + m] = (float)sv;
    }

    for (int pair = tid; pair < KK * C_; pair += 256) {
        int k = pair >> 6, c = pair & 63;
        const float* xcp = xc + selI[k] * XCSTR + c * 9;
        const float* ycp = ysE + c * 9;
        float a = 0.f;
        #pragma unroll
        for (int p = 0; p < 9; p++) a += fabsf(ycp[p] - xcp[p]);
        dsum_ws[((b * KK + k) * C_ + c) * NP + m] = a;
    }
}

// ---------------- overlap-add image kernels ---------------------------------
__device__ __forceinline__ void oa_range(int y, int& r0, int& r1) {
    r0 = (y >= 5) ? ((y - 4) >> 1) : 0;
    r1 = min(M1 - 1, y >> 1);
}

__global__ __launch_bounds__(256) void score_img_kernel(const float* __restrict__ sv_ws,
                                                        float* __restrict__ out) {
    int idx = blockIdx.x * 256 + threadIdx.x;
    if (idx >= OUT_SCORE_SZ) return;
    int x = idx & 127, y = (idx >> 7) & 127;
    int bk = idx >> 14;
    int r0, r1, s0, s1;
    oa_range(y, r0, r1);
    oa_range(x, s0, s1);
    const float* base = sv_ws + bk * NP;
    float acc = 0.f;
    for (int rr = r0; rr <= r1; rr++)
        for (int ss = s0; ss <= s1; ss++)
            acc += base[rr * M1 + ss];
    out[idx] = acc;
}

__global__ __launch_bounds__(256) void diff_img_kernel(const float* __restrict__ dsum_ws,
                                                       float* __restrict__ out) {
    int idx = blockIdx.x * 256 + threadIdx.x;
    if (idx >= OUT_DIFF_SZ) return;
    int x = idx & 127, y = (idx >> 7) & 127;
    int bkc = idx >> 14;
    int r0, r1, s0, s1;
    oa_range(y, r0, r1);
    oa_range(x, s0, s1);
    const float* base = dsum_ws + bkc * NP;
    float acc = 0.f;
    for (int rr = r0; rr <= r1; rr++)
        for (int ss = s0; ss <= s1; ss++)
            acc += base[rr * M1 + ss];
    out[idx] = acc;
}

extern "C" void kernel_launch(void* const* d_in, const int* in_sizes, int n_in,
                              void* d_out, int out_size, void* d_ws, size_t ws_size,
                              hipStream_t stream) {
    const float* xe = (const float*)d_in[0];
    const float* ye = (const float*)d_in[1];
    float* out = (float*)d_out;
    float* ws = (float*)d_ws;

    float* xnp = ws + WS_XNP;
    float* ynp = ws + WS_YNP;
    int*   topw = (int*)(ws + WS_TOP);
    float* sv_ws = ws + WS_SV;
    float* dsum_ws = ws + WS_DSUM;
    float* xpm = ws + WS_XPM;
    float* ypm = ws + WS_YPM;
    unsigned int* ypbfW = (unsigned int*)(ws + WS_YPBF);
    unsigned int* xebfW = (unsigned int*)(ws + WS_XEBF);

    const bool pm_ok = (ws_size >= WS_NEED_BYTES);

    if (pm_ok) {
        prep_xebf_kernel<<<B_ * HW, 256, 0, stream>>>(xe, xebfW);
        im2patch_kernel<<<2 * B_ * M1, 256, 0, stream>>>(xe, ye, xpm, ypm, ypbfW);
    }
    norm_np_kernel<<<(2 * B_ * NP * 8 + 255) / 256, 256, 0, stream>>>(xe, ye, xnp, ynp);
    gemm_select_kernel<<<2 * 256, 512, 0, stream>>>(xe, ye,
                                                    (const unsigned short*)ypbfW,
                                                    (const unsigned short*)xebfW,
                                                    xnp, topw, pm_ok ? 1 : 0);
    if (pm_ok) {
        emu_pm_kernel<<<B_ * NP, 256, 0, stream>>>(xpm, ypm, xnp, ynp, topw,
                                                   out + OUT_IDX_OFF, sv_ws, dsum_ws);
    } else {
        emu_fallback_kernel<<<B_ * NP, 256, 0, stream>>>(xe, ye, xnp, ynp, topw,
                                                         out + OUT_IDX_OFF, sv_ws, dsum_ws);
    }
    score_img_kernel<<<OUT_SCORE_SZ / 256, 256, 0, stream>>>(sv_ws, out);
    diff_img_kernel<<<OUT_DIFF_SZ / 256, 256, 0, stream>>>(dsum_ws, out + OUT_DIFF_OFF);
}

// Round 14
// 178.311 us; speedup vs baseline: 1.1953x; 1.1953x over previous
//
#include <hip/hip_runtime.h>
#include <float.h>
#include <math.h>

#define B_ 2
#define C_ 64
#define HW 64
#define M1 62
#define NP (M1*M1)      // 3844
#define WIN 30
#define KK 5
#define NSEL 16
#define HS 128

#define OUT_SCORE_SZ (B_*KK*HS*HS)       // 163840
#define OUT_IDX_OFF  (OUT_SCORE_SZ)
#define OUT_IDX_SZ   (B_*NP*KK)          // 38440
#define OUT_DIFF_OFF (OUT_IDX_OFF+OUT_IDX_SZ)
#define OUT_DIFF_SZ  (B_*KK*C_*HS*HS)    // 10485760

// ws layout in floats
#define WS_XNP 0
#define WS_YNP 8192
#define WS_TOP 16384                      // ints: B_*NP*16 = 123008
#define WS_SV  (16384+123008)             // 139392
#define WS_DSUM (139392+40960)            // 180352
#define WS_XPM  (180352+2460160)          // 2640512
#define XPM_F   (B_*NP*576)               // 4428288 floats
#define WS_YPM  (WS_XPM + XPM_F)          // 7068800
#define WS_YPBF (WS_YPM + XPM_F)          // 11497088 (ushorts: B_*NP*576)
#define WS_XEBF (WS_YPBF + XPM_F/2)       // 13711232 (ushorts: B_*64*64*64)
#define WS_END  (WS_XEBF + 262144)        // 13973376
#define WS_NEED_BYTES ((size_t)WS_END * 4)   // ~55.9 MB

typedef __attribute__((ext_vector_type(8))) short bf16x8;
typedef __attribute__((ext_vector_type(4))) short bf16x4;
typedef __attribute__((ext_vector_type(4))) short s16x4;
typedef __attribute__((ext_vector_type(4))) float f32x4;

__device__ __forceinline__ unsigned short f2bf(float f) {
    union { float f; unsigned int u; } v; v.f = f;
    unsigned int r = (v.u + 0x7FFFu + ((v.u >> 16) & 1u)) >> 16;
    return (unsigned short)r;
}

__device__ __forceinline__ bf16x8 ld_bf8(const short* p) {
    bf16x4 lo = *(const bf16x4*)p;
    bf16x4 hi = *(const bf16x4*)(p + 4);
    bf16x8 r;
    r[0] = lo[0]; r[1] = lo[1]; r[2] = lo[2]; r[3] = lo[3];
    r[4] = hi[0]; r[5] = hi[1]; r[6] = hi[2]; r[7] = hi[3];
    return r;
}

// ---------------- K-1: xe -> pixel-major bf16 copy xebf[b][h][w][c] ---------
__global__ __launch_bounds__(256) void prep_xebf_kernel(const float* __restrict__ xe,
                                                        unsigned int* __restrict__ xebfW) {
    __shared__ float tile[64 * 65];
    const int bid = blockIdx.x;           // b*64 + h
    const int b = bid >> 6, h = bid & 63;
    const int tid = threadIdx.x;
    for (int i = tid; i < 4096; i += 256) {
        int c = i >> 6, w = i & 63;
        tile[c * 65 + w] = xe[(((size_t)b * C_ + c) * HW + h) * HW + w];
    }
    __syncthreads();
    for (int j = tid; j < 2048; j += 256) {
        int w = j >> 5, cp = j & 31;
        unsigned int u = (unsigned int)f2bf(tile[(2 * cp) * 65 + w])
                       | ((unsigned int)f2bf(tile[(2 * cp + 1) * 65 + w]) << 16);
        xebfW[(((size_t)b * HW + h) * HW + w) * 32 + cp] = u;
    }
}

// ---------------- K0: im2patch (f32 patch-major + permuted bf16 y) ----------
__global__ __launch_bounds__(256) void im2patch_kernel(const float* __restrict__ xe,
                                                       const float* __restrict__ ye,
                                                       float* __restrict__ xpm,
                                                       float* __restrict__ ypm,
                                                       unsigned int* __restrict__ ypbfW) {
    __shared__ float rows[64 * 192];
    __shared__ int tabL[576];
    __shared__ int tabP[576];
    const int tid = threadIdx.x;
    const int bid = blockIdx.x;
    const int srcI = bid / (B_ * M1);
    const int rem = bid - srcI * (B_ * M1);
    const int b = rem / M1, r = rem - b * M1;
    const float* src = (srcI ? ye : xe) + (size_t)b * C_ * HW * HW;
    float* dst = (srcI ? ypm : xpm) + (size_t)(b * NP + r * M1) * 576;

    for (int t = tid; t < 576; t += 256) {
        int c = t / 9, p = t - c * 9;
        tabL[t] = c * 192 + (p / 3) * 64 + (p % 3);
        int cj = (t / 144) * 16 + (t & 15), pj = (t % 144) >> 4;   // decode j
        tabP[t] = cj * 192 + (pj / 3) * 64 + (pj % 3);
    }
    for (int i = tid; i < 64 * 192; i += 256) {
        rows[i] = src[(i / 192) * (HW * HW) + r * HW + (i % 192)];
    }
    __syncthreads();

    for (int s = 0; s < M1; s++) {
        float* d = dst + s * 576;
        for (int e = tid; e < 576; e += 256) d[e] = rows[tabL[e] + s];
        if (srcI) {
            unsigned int* yb = ypbfW + (size_t)(b * NP + r * M1 + s) * 288;
            for (int j2 = tid; j2 < 288; j2 += 256) {
                unsigned int u = (unsigned int)f2bf(rows[tabP[2 * j2] + s])
                               | ((unsigned int)f2bf(rows[tabP[2 * j2 + 1] + s]) << 16);
                yb[j2] = u;
            }
        }
    }
}

// ---------------- K1a: numpy-pairwise norms, dense reads from pm ------------
// Same leaf (72, scalar 8-acc) + tree structure as before; values are copies
// so all float ops are bit-identical.
__global__ __launch_bounds__(256) void norm_np_pm_kernel(const float* __restrict__ xpm,
                                                         const float* __restrict__ ypm,
                                                         float* __restrict__ xnp,
                                                         float* __restrict__ ynp) {
    int gid = blockIdx.x * 256 + threadIdx.x;
    if (gid >= 2 * B_ * NP * 8) return;
    int which = gid / (B_ * NP * 8);
    int rem = gid - which * (B_ * NP * 8);
    int patch = rem >> 3, leaf = rem & 7;
    const float* src = (which ? ypm : xpm) + (size_t)patch * 576 + leaf * 72;

    float a8[8];
    #pragma unroll
    for (int i = 0; i < 8; i++) { float v = src[i]; a8[i] = v * v; }
    for (int i0 = 8; i0 < 72; i0 += 8) {
        #pragma unroll
        for (int i = 0; i < 8; i++) { float v = src[i0 + i]; a8[i] += v * v; }
    }
    float t = ((a8[0] + a8[1]) + (a8[2] + a8[3])) + ((a8[4] + a8[5]) + (a8[6] + a8[7]));
    t = t + __shfl_xor(t, 1, 8);
    t = t + __shfl_xor(t, 2, 8);
    t = t + __shfl_xor(t, 4, 8);
    if (leaf == 0) (which ? ynp : xnp)[patch] = t;
}

// ---------------- K1b: fallback norms (scattered) ---------------------------
__global__ __launch_bounds__(256) void norm_np_kernel(const float* __restrict__ xe,
                                                      const float* __restrict__ ye,
                                                      float* __restrict__ xnp,
                                                      float* __restrict__ ynp) {
    __shared__ int tab[576];
    for (int t = threadIdx.x; t < 576; t += 256) {
        int c = t / 9, p = t - c * 9;
        tab[t] = c * (HW * HW) + (p / 3) * HW + (p % 3);
    }
    __syncthreads();

    int gid = blockIdx.x * 256 + threadIdx.x;
    if (gid >= 2 * B_ * NP * 8) return;
    int which = gid / (B_ * NP * 8);
    int rem = gid - which * (B_ * NP * 8);
    int patch = rem >> 3, leaf = rem & 7;
    int b = patch / NP, m = patch - b * NP;
    int r = m / M1, s = m - r * M1;
    const float* src = (which ? ye : xe) + (size_t)b * C_ * HW * HW + r * HW + s;

    int base = leaf * 72;
    float a8[8];
    #pragma unroll
    for (int i = 0; i < 8; i++) { float v = src[tab[base + i]]; a8[i] = v * v; }
    for (int i0 = 8; i0 < 72; i0 += 8) {
        #pragma unroll
        for (int i = 0; i < 8; i++) { float v = src[tab[base + i0 + i]]; a8[i] += v * v; }
    }
    float t = ((a8[0] + a8[1]) + (a8[2] + a8[3])) + ((a8[4] + a8[5]) + (a8[6] + a8[7]));
    t = t + __shfl_xor(t, 1, 8);
    t = t + __shfl_xor(t, 2, 8);
    t = t + __shfl_xor(t, 4, 8);
    if (leaf == 0) (which ? ynp : xnp)[patch] = t;
}

// ---------------- K2: MFMA prescreen, 16-ch chunks, 2 blocks/CU -------------
#define UPC2 40
#define CSTR2 20
#define YSTR2 580
#define ZOFF_SH (16*YSTR2)
#define YS2_OFF 56000
#define XN2_OFF (YS2_OFF + (ZOFF_SH+16)*2)
#define SM2_BYTES (XN2_OFF + 1089*4)

__global__ __launch_bounds__(512, 4) void gemm_select_kernel(const float* __restrict__ xe,
                                                             const float* __restrict__ ye,
                                                             const unsigned short* __restrict__ ypbf,
                                                             const unsigned short* __restrict__ xebf,
                                                             const float* __restrict__ xnp,
                                                             int* __restrict__ top_ws,
                                                             int use_pm) {
    __shared__ __align__(16) unsigned char smem[SM2_BYTES];
    short* xsS = (short*)smem;
    unsigned int* xsW = (unsigned int*)smem;
    short* ysS = (short*)(smem + YS2_OFF);
    float* xnL = (float*)(smem + XN2_OFF);
    float* Dl  = (float*)smem;

    const int bid = blockIdx.x;
    const int b  = bid >> 8;
    const int t  = bid & 255;
    const int r0 = (t >> 4) * 4;
    const int s0 = (t & 15) * 4;
    const int u0r = min(max(r0 - 15, 0), 32);
    const int u0c = min(max(s0 - 15, 0), 32);
    const int g0c = min(u0c & ~3, 24);
    const int cofs = u0c - g0c;
    const int tid = threadIdx.x;
    const int l   = tid & 63;
    const int wid = tid >> 6;
    const int lq  = l & 15;
    const int kg  = l >> 4;
    const int kgh = kg >> 1, kgl = kg & 1;

    if (use_pm) {
        for (int u = tid; u < 16 * 144; u += 512) {
            int q = u / 144, j4 = u - q * 144;
            int rq = min(r0 + (q >> 2), 61), sq = min(s0 + (q & 3), 61);
            s16x4 v = *(const s16x4*)(ypbf + (size_t)(b * NP + rq * M1 + sq) * 576 + j4 * 4);
            *(s16x4*)(ysS + q * YSTR2 + j4 * 4) = v;
        }
    } else {
        for (int u = tid; u < 16 * 576; u += 512) {
            int q = u / 576, e = u - q * 576;
            int rq = min(r0 + (q >> 2), 61), sq = min(s0 + (q & 3), 61);
            int c = e / 9, p = e - c * 9;
            float v = ye[((b * C_ + c) * HW + rq + p / 3) * HW + sq + p % 3];
            ysS[q * YSTR2 + (c >> 4) * 144 + p * 16 + (c & 15)] = (short)f2bf(v);
        }
    }
    if (tid < 16) ysS[ZOFF_SH + tid] = 0;
    for (int i = tid; i < 1089; i += 512) {
        int cr = i / 33, cc = i - cr * 33;
        int nr = min(u0r + cr, 61), nc = min(u0c + cc, 61);
        xnL[i] = xnp[b * NP + nr * M1 + nc];
    }

    f32x4 acc[10];
    #pragma unroll
    for (int i = 0; i < 10; i++) acc[i] = (f32x4){0.f, 0.f, 0.f, 0.f};

    const int PI0[4] = {0, 0, 1, 2}, PJ0[4] = {0, 2, 1, 0};
    const int PI1[4] = {0, 1, 1, 2}, PJ1[4] = {1, 0, 2, 1};

    int prb[10], pcb[10];
    #pragma unroll
    for (int i = 0; i < 10; i++) {
        int ci = (wid * 10 + i) * 16 + lq;
        int cis = min(ci, 1088);
        int cr = cis / 33;
        prb[i] = cr;
        pcb[i] = cis - cr * 33 + cofs;
    }

    for (int chunk = 0; chunk < 4; chunk++) {
        __syncthreads();
        if (use_pm) {
            for (int u = tid; u < 35 * 40 * 4; u += 512) {
                int pix = u >> 2, q4 = u & 3;
                int row = pix / 40, col = pix - row * 40;
                int gr = min(u0r + row, 63);
                s16x4 v = *(const s16x4*)(xebf + ((((size_t)b * HW + gr) * HW + g0c + col) << 6)
                                          + chunk * 16 + q4 * 4);
                *(s16x4*)(xsS + pix * CSTR2 + q4 * 4) = v;
            }
        } else {
            for (int u = tid; u < 560; u += 512) {
                int cp = u & 7, rh = u >> 3;
                int row = rh % 35, half = rh / 35;
                int c0 = chunk * 16 + cp * 2;
                int gr = min(u0r + row, 63);
                const float4* pa = (const float4*)(xe + ((size_t)(b * C_ + c0) * HW + gr) * HW + g0c);
                const float4* pb = (const float4*)(xe + ((size_t)(b * C_ + c0 + 1) * HW + gr) * HW + g0c);
                #pragma unroll
                for (int bb = 0; bb < 5; bb++) {
                    int blk = half * 5 + bb;
                    float4 va = pa[blk], vb = pb[blk];
                    int w0 = (row * UPC2 + blk * 4) * (CSTR2 / 2) + cp;
                    xsW[w0     ] = (unsigned)f2bf(va.x) | ((unsigned)f2bf(vb.x) << 16);
                    xsW[w0 + 10] = (unsigned)f2bf(va.y) | ((unsigned)f2bf(vb.y) << 16);
                    xsW[w0 + 20] = (unsigned)f2bf(va.z) | ((unsigned)f2bf(vb.z) << 16);
                    xsW[w0 + 30] = (unsigned)f2bf(va.w) | ((unsigned)f2bf(vb.w) << 16);
                }
            }
        }
        __syncthreads();

        const int aBase = lq * YSTR2 + chunk * 144;
        #pragma unroll
        for (int t4 = 0; t4 < 5; t4++) {
            bf16x8 af;
            int pi, pj;
            if (t4 < 4) {
                int p = 2 * t4 + kgh;
                af = ld_bf8(ysS + aBase + p * 16 + kgl * 8);
                pi = kgh ? PI1[t4] : PI0[t4];
                pj = kgh ? PJ1[t4] : PJ0[t4];
            } else {
                af = ld_bf8(ysS + ((kg < 2) ? (aBase + 8 * 16 + kgl * 8) : (ZOFF_SH + kgl * 8)));
                pi = 2; pj = 2;
            }
            #pragma unroll
            for (int i = 0; i < 10; i++) {
                bf16x8 bf = ld_bf8(xsS + ((prb[i] + pi) * UPC2 + (pcb[i] + pj)) * CSTR2 + kgl * 8);
                acc[i] = __builtin_amdgcn_mfma_f32_16x16x32_bf16(af, bf, acc[i], 0, 0, 0);
            }
        }
    }

    __syncthreads();
    #pragma unroll
    for (int i = 0; i < 10; i++) {
        int ci = (wid * 10 + i) * 16 + lq;
        if (ci < 1089) {
            float xnv = xnL[ci];
            #pragma unroll
            for (int j = 0; j < 4; j++) {
                Dl[(kg * 4 + j) * 1089 + ci] = xnv - 2.0f * acc[i][j];
            }
        }
    }
    __syncthreads();

    for (int qq = 0; qq < 2; qq++) {
        int q = wid * 2 + qq;
        int rq = r0 + (q >> 2), sq = s0 + (q & 3);
        if (rq > 61 || sq > 61) continue;
        int siq = min(max(rq - 15, 0), 32);
        int sjq = min(max(sq - 15, 0), 32);
        int ro = siq - u0r, co = sjq - u0c;
        unsigned int kv[15];
        #pragma unroll
        for (int kk = 0; kk < 15; kk++) {
            int w = kk * 64 + l;
            if (w < 900) {
                int wi = w / 30, wj = w - wi * 30;
                float v = Dl[q * 1089 + (ro + wi) * 33 + (co + wj)];
                unsigned int u = __float_as_uint(v);
                u ^= (unsigned int)((int)u >> 31) | 0x80000000u;
                kv[kk] = (u & 0xFFFFFC00u) | (unsigned int)w;
            } else kv[kk] = 0xFFFFFFFFu;
        }
        int obase = (b * NP + rq * M1 + sq) * NSEL;
        for (int it = 0; it < NSEL; it++) {
            unsigned int lm = kv[0];
            #pragma unroll
            for (int kk = 1; kk < 15; kk++) lm = min(lm, kv[kk]);
            #pragma unroll
            for (int off = 32; off >= 1; off >>= 1)
                lm = min(lm, (unsigned int)__shfl_xor((int)lm, off));
            if (l == 0) {
                int w = (int)(lm & 1023u);
                int wi = w / 30, wj = w - wi * 30;
                top_ws[obase + it] = (siq + wi) * M1 + (sjq + wj);
            }
            #pragma unroll
            for (int kk = 0; kk < 15; kk++)
                if (kv[kk] == lm) kv[kk] = 0xFFFFFFFFu;
        }
    }
}

// ---------------- K3a: emu from patch-major buffers (dense reads) -----------
__global__ __launch_bounds__(256) void emu_pm_kernel(const float* __restrict__ xpm,
                                                     const float* __restrict__ ypm,
                                                     const float* __restrict__ xnp,
                                                     const float* __restrict__ ynp,
                                                     const int* __restrict__ top_ws,
                                                     float* __restrict__ out_idx,
                                                     float* __restrict__ sv_ws,
                                                     float* __restrict__ dsum_ws) {
    __shared__ float ysE[576];
    __shared__ int topWs[NSEL];
    __shared__ float keyEmu[NSEL];
    __shared__ float selKey[KK];
    __shared__ int   selN[KK];

    const int bid0 = blockIdx.x;
    const int bid = (bid0 & 7) * (B_ * NP / 8) + (bid0 >> 3);  // XCD-affine
    const int b = bid / NP, m = bid - b * NP;
    const int tid = threadIdx.x;
    const float* ybase = ypm + (size_t)(b * NP + m) * 576;

    for (int t = tid; t < 576; t += 256) ysE[t] = ybase[t];
    if (tid < NSEL) topWs[tid] = top_ws[bid * NSEL + tid];
    __syncthreads();

    {
        const int cand = tid >> 4, j = tid & 15;
        const float* xp = xpm + (size_t)(b * NP + topWs[cand]) * 576;
        float acc = 0.f;
        #pragma unroll
        for (int t = 0; t < 36; t++) {
            int e = t * 16 + j;
            acc = fmaf(ysE[e], xp[e], acc);
        }
        float E = acc;
        E = E + __shfl_xor(E, 8, 16);
        E = E + __shfl_xor(E, 4, 16);
        E = E + __shfl_xor(E, 2, 16);
        E = E + __shfl_xor(E, 1, 16);
        if (j == 0) {
            float t0 = -2.0f * E;
            float k1 = t0 + ynp[b * NP + m];
            float k2 = k1 + xnp[b * NP + topWs[cand]];
            keyEmu[cand] = k2 + 1e-5f;
        }
    }
    __syncthreads();

    if (tid == 0) {
        float d[NSEL]; int w[NSEL];
        for (int i = 0; i < NSEL; i++) { d[i] = keyEmu[i]; w[i] = topWs[i]; }
        for (int a = 1; a < NSEL; a++) {
            float dv = d[a]; int wv2 = w[a]; int p = a - 1;
            while (p >= 0 && (d[p] > dv || (d[p] == dv && w[p] > wv2))) {
                d[p + 1] = d[p]; w[p + 1] = w[p]; p--;
            }
            d[p + 1] = dv; w[p + 1] = wv2;
        }
        for (int i = 0; i < KK; i++) { selKey[i] = d[i]; selN[i] = w[i]; }
    }
    __syncthreads();

    if (tid < KK) {
        out_idx[(b * NP + m) * KK + tid] = (float)selN[tid];
        float s10 = selKey[tid] / 10.0f;
        double sv = exp(-(double)s10);
        sv_ws[(b * KK + tid) * NP + m] = (float)sv;
    }

    for (int pair = tid; pair < KK * C_; pair += 256) {
        int k = pair >> 6, c = pair & 63;
        const float* xrow = xpm + (size_t)(b * NP + selN[k]) * 576 + c * 9;
        const float* yrow = ysE + c * 9;
        float a = 0.f;
        #pragma unroll
        for (int p = 0; p < 9; p++) a += fabsf(yrow[p] - xrow[p]);
        dsum_ws[((b * KK + k) * C_ + c) * NP + m] = a;
    }
}

// ---------------- K3b: fallback emu (scattered) ------------------------------
#define XCSTR 584

__global__ __launch_bounds__(256) void emu_fallback_kernel(const float* __restrict__ xe,
                                                           const float* __restrict__ ye,
                                                           const float* __restrict__ xnp,
                                                           const float* __restrict__ ynp,
                                                           const int* __restrict__ top_ws,
                                                           float* __restrict__ out_idx,
                                                           float* __restrict__ sv_ws,
                                                           float* __restrict__ dsum_ws) {
    __shared__ float ysE[576];
    __shared__ int tab[576];
    __shared__ float xc[NSEL * XCSTR];
    __shared__ int topWs[NSEL];
    __shared__ float keyEmu[NSEL];
    __shared__ float selKey[KK];
    __shared__ int   selN[KK];
    __shared__ int   selI[KK];

    const int bid0 = blockIdx.x;
    const int bid = (bid0 & 7) * (B_ * NP / 8) + (bid0 >> 3);
    const int b = bid / NP, m = bid - b * NP;
    const int r = m / M1, s = m - r * M1;
    const int tid = threadIdx.x;
    const float* xb = xe + (size_t)b * C_ * HW * HW;
    const float* yb = ye + (size_t)b * C_ * HW * HW + r * HW + s;

    for (int t = tid; t < 576; t += 256) {
        int c = t / 9, p = t - c * 9;
        tab[t] = c * (HW * HW) + (p / 3) * HW + (p % 3);
    }
    if (tid < NSEL) topWs[tid] = top_ws[bid * NSEL + tid];
    __syncthreads();

    for (int t = tid; t < 576; t += 256) ysE[t] = yb[tab[t]];
    for (int i = tid; i < NSEL * 576; i += 256) {
        int cand = i / 576, e = i - cand * 576;
        int n = topWs[cand];
        int px = n / M1, py = n - px * M1;
        xc[cand * XCSTR + e] = xb[px * HW + py + tab[e]];
    }
    __syncthreads();

    {
        const int cand = tid >> 4, j = tid & 15;
        const float* xcp = xc + cand * XCSTR;
        float acc = 0.f;
        #pragma unroll
        for (int t = 0; t < 36; t++) {
            int e = t * 16 + j;
            acc = fmaf(ysE[e], xcp[e], acc);
        }
        float E = acc;
        E = E + __shfl_xor(E, 8, 16);
        E = E + __shfl_xor(E, 4, 16);
        E = E + __shfl_xor(E, 2, 16);
        E = E + __shfl_xor(E, 1, 16);
        if (j == 0) {
            float t0 = -2.0f * E;
            float k1 = t0 + ynp[b * NP + m];
            float k2 = k1 + xnp[b * NP + topWs[cand]];
            keyEmu[cand] = k2 + 1e-5f;
        }
    }
    __syncthreads();

    if (tid == 0) {
        float d[NSEL]; int w[NSEL]; int ix[NSEL];
        for (int i = 0; i < NSEL; i++) { d[i] = keyEmu[i]; w[i] = topWs[i]; ix[i] = i; }
        for (int a = 1; a < NSEL; a++) {
            float dv = d[a]; int wv2 = w[a]; int iv = ix[a]; int p = a - 1;
            while (p >= 0 && (d[p] > dv || (d[p] == dv && w[p] > wv2))) {
                d[p + 1] = d[p]; w[p + 1] = w[p]; ix[p + 1] = ix[p]; p--;
            }
            d[p + 1] = dv; w[p + 1] = wv2; ix[p + 1] = iv;
        }
        for (int i = 0; i < KK; i++) { selKey[i] = d[i]; selN[i] = w[i]; selI[i] = ix[i]; }
    }
    __syncthreads();

    if (tid < KK) {
        out_idx[(b * NP + m) * KK + tid] = (float)selN[tid];
        float s10 = selKey[tid] / 10.0f;
        double sv = exp(-(double)s10);
        sv_ws[(b * KK + tid) * NP + m] = (float)sv;
    }

    for (int pair = tid; pair < KK * C_; pair += 256) {
        int k = pair >> 6, c = pair & 63;
        const float* xcp = xc + selI[k] * XCSTR + c * 9;
        const float* ycp = ysE + c * 9;
        float a = 0.f;
        #pragma unroll
        for (int p = 0; p < 9; p++) a += fabsf(ycp[p] - xcp[p]);
        dsum_ws[((b * KK + k) * C_ + c) * NP + m] = a;
    }
}

// ---------------- overlap-add image kernels ---------------------------------
__device__ __forceinline__ void oa_range(int y, int& r0, int& r1) {
    r0 = (y >= 5) ? ((y - 4) >> 1) : 0;
    r1 = min(M1 - 1, y >> 1);
}

__global__ __launch_bounds__(256) void score_img_kernel(const float* __restrict__ sv_ws,
                                                        float* __restrict__ out) {
    int idx = blockIdx.x * 256 + threadIdx.x;
    if (idx >= OUT_SCORE_SZ) return;
    int x = idx & 127, y = (idx >> 7) & 127;
    int bk = idx >> 14;
    int r0, r1, s0, s1;
    oa_range(y, r0, r1);
    oa_range(x, s0, s1);
    const float* base = sv_ws + bk * NP;
    float acc = 0.f;
    for (int rr = r0; rr <= r1; rr++)
        for (int ss = s0; ss <= s1; ss++)
            acc += base[rr * M1 + ss];
    out[idx] = acc;
}

// separable per-plane overlap-add: row pass into LDS, then col pass.
__global__ __launch_bounds__(256) void diff_img_sep_kernel(const float* __restrict__ dsum_ws,
                                                           float* __restrict__ out) {
    __shared__ float dpl[NP];             // 62*62 = 15.4KB
    __shared__ float trow[M1 * HS];       // 62*128 = 31.7KB
    const int bkc = blockIdx.x;           // [0,640)
    const int tid = threadIdx.x;
    const float* src = dsum_ws + (size_t)bkc * NP;

    for (int i = tid; i < NP; i += 256) dpl[i] = src[i];
    __syncthreads();

    for (int u = tid; u < M1 * HS; u += 256) {
        int rr = u >> 7, x = u & 127;
        int s0, s1;
        oa_range(x, s0, s1);
        const float* dr = dpl + rr * M1;
        float a = 0.f;
        for (int ss = s0; ss <= s1; ss++) a += dr[ss];
        trow[rr * HS + x] = a;
    }
    __syncthreads();

    float* dst = out + (size_t)bkc * (HS * HS);
    for (int u = tid; u < HS * HS; u += 256) {
        int y = u >> 7, x = u & 127;
        int r0, r1;
        oa_range(y, r0, r1);
        float a = 0.f;
        for (int rr = r0; rr <= r1; rr++) a += trow[rr * HS + x];
        dst[u] = a;
    }
}

extern "C" void kernel_launch(void* const* d_in, const int* in_sizes, int n_in,
                              void* d_out, int out_size, void* d_ws, size_t ws_size,
                              hipStream_t stream) {
    const float* xe = (const float*)d_in[0];
    const float* ye = (const float*)d_in[1];
    float* out = (float*)d_out;
    float* ws = (float*)d_ws;

    float* xnp = ws + WS_XNP;
    float* ynp = ws + WS_YNP;
    int*   topw = (int*)(ws + WS_TOP);
    float* sv_ws = ws + WS_SV;
    float* dsum_ws = ws + WS_DSUM;
    float* xpm = ws + WS_XPM;
    float* ypm = ws + WS_YPM;
    unsigned int* ypbfW = (unsigned int*)(ws + WS_YPBF);
    unsigned int* xebfW = (unsigned int*)(ws + WS_XEBF);

    const bool pm_ok = (ws_size >= WS_NEED_BYTES);

    if (pm_ok) {
        prep_xebf_kernel<<<B_ * HW, 256, 0, stream>>>(xe, xebfW);
        im2patch_kernel<<<2 * B_ * M1, 256, 0, stream>>>(xe, ye, xpm, ypm, ypbfW);
        norm_np_pm_kernel<<<(2 * B_ * NP * 8 + 255) / 256, 256, 0, stream>>>(xpm, ypm, xnp, ynp);
    } else {
        norm_np_kernel<<<(2 * B_ * NP * 8 + 255) / 256, 256, 0, stream>>>(xe, ye, xnp, ynp);
    }
    gemm_select_kernel<<<2 * 256, 512, 0, stream>>>(xe, ye,
                                                    (const unsigned short*)ypbfW,
                                                    (const unsigned short*)xebfW,
                                                    xnp, topw, pm_ok ? 1 : 0);
    if (pm_ok) {
        emu_pm_kernel<<<B_ * NP, 256, 0, stream>>>(xpm, ypm, xnp, ynp, topw,
                                                   out + OUT_IDX_OFF, sv_ws, dsum_ws);
    } else {
        emu_fallback_kernel<<<B_ * NP, 256, 0, stream>>>(xe, ye, xnp, ynp, topw,
                                                         out + OUT_IDX_OFF, sv_ws, dsum_ws);
    }
    score_img_kernel<<<OUT_SCORE_SZ / 256, 256, 0, stream>>>(sv_ws, out);
    diff_img_sep_kernel<<<B_ * KK * C_, 256, 0, stream>>>(dsum_ws, out + OUT_DIFF_OFF);
}